// Round 1
// 77.604 us; speedup vs baseline: 1.0168x; 1.0168x over previous
//
#include <hip/hip_runtime.h>
#include <math.h>

// KANConv2D via bf16 MFMA 16x16x32, R7.
// - cvt kernel pre-swizzles fp32 weights -> bf16 MFMA B-frag streams in d_ws
//   (d_ws poison cost is fixed harness overhead; using it is free).
// - Main: 392 blocks (4 b x 14x7 tiles of 4x8 px, M=32), 512 thr = 8 waves.
//   R7 wave decomposition: wave = (nq 0..3: oc quarter of 16) x (kh 0..1: K half).
//   Each wave covers M=32 (two A-frags, two INDEPENDENT acc chains per B-frag):
//   * dependent-MFMA chain depth per acc: 72 -> 36 (latency-bound fix)
//   * per-wave B-frag L2 traffic halves (each wst element read once per block)
//   Cross-wave K reduction via LDS SoA (conflict-free), kh=0 waves do epilogue.
// Frag maps (validated by passing R1/R6 kernels / m89/m120):
//   A: m = lane&15 (+16 for frag1), k = (lane>>4)*8 + j
//   B: n = lane&15, k = (lane>>4)*8 + j
//   C/D: col = lane&15 = n, row = (lane>>4)*4 + reg = m (+16 for frag1).

typedef __attribute__((ext_vector_type(8))) short bf16x8;
typedef __attribute__((ext_vector_type(4))) float f32x4;

#define MFMA16(a, b, c) __builtin_amdgcn_mfma_f32_16x16x32_bf16((a), (b), (c), 0, 0, 0)

__device__ __forceinline__ unsigned short f2bf(float f) {
    unsigned u = __builtin_bit_cast(unsigned, f);
    u = (u + 0x7fffu + ((u >> 16) & 1u)) >> 16;   // RNE
    return (unsigned short)u;
}

__device__ __forceinline__ void eval_bases(float v, float bs[8]) {
    #pragma unroll
    for (int i = 0; i < 8; ++i) bs[i] = 0.0f;
    // knots: t_g = (g-3)*0.4 - 1, support [-2.2, 2.2)
    float t = (v + 2.2f) * 2.5f;
    if (t >= 0.0f && t < 11.0f) {
        int j = (int)t;
        if (j > 10) j = 10;
        float knot = (float)(j - 3) * 0.4f - 1.0f;
        float u  = (v - knot) * 2.5f;
        float um = 1.0f - u;
        float u2 = u * u, u3 = u2 * u;
        const float s6 = 1.0f / 6.0f;
        float w0 = um * um * um * s6;
        float w1 = (3.0f * u3 - 6.0f * u2 + 4.0f) * s6;
        float w2 = (-3.0f * u3 + 3.0f * u2 + 3.0f * u + 1.0f) * s6;
        float w3 = u3 * s6;
        int i0 = j - 3;
        if (i0 >= 0)               bs[i0]     = w0;
        if (i0 + 1 >= 0 && i0 < 7) bs[i0 + 1] = w1;
        if (i0 + 2 >= 0 && i0 < 6) bs[i0 + 2] = w2;
        if (i0 + 3 <= 7)           bs[i0 + 3] = w3;
    }
}

// ---- pre-kernel: fp32 weights -> bf16 B-frag streams (16x16x32 layout) ----
// wst[((nq*72 + S)*64 + lane)*8 + j] = ws[(nq*16 + (lane&15))*2304 + S*32 + (lane>>4)*8 + j]
// wbt[((nq*9  + s)*64 + lane)*8 + j] = wb[(nq*16 + (lane&15))*288  + s*32 + (lane>>4)*8 + j]
__global__ __launch_bounds__(256)
void cvt_swz_kernel(const float* __restrict__ ws, const float* __restrict__ wb,
                    unsigned short* __restrict__ wst, unsigned short* __restrict__ wbt) {
    int i = blockIdx.x * 256 + threadIdx.x;
    if (i < 147456) {
        int j = i & 7, l = (i >> 3) & 63, t = i >> 9;   // t 0..287
        int S = t % 72, nq = t / 72;
        int oc = nq * 16 + (l & 15);
        int k  = S * 32 + (l >> 4) * 8 + j;
        wst[i] = f2bf(ws[oc * 2304 + k]);
    } else {
        int i2 = i - 147456;
        if (i2 < 18432) {
            int j = i2 & 7, l = (i2 >> 3) & 63, t = i2 >> 9;  // t 0..35
            int s = t % 9, nq = t / 9;
            int oc = nq * 16 + (l & 15);
            int k  = s * 32 + (l >> 4) * 8 + j;
            wbt[i2] = f2bf(wb[oc * 288 + k]);
        }
    }
}

__global__ __launch_bounds__(512)
void kan_mfma_kernel(const float* __restrict__ x,
                     const float* __restrict__ sc,
                     const unsigned short* __restrict__ wst,
                     const unsigned short* __restrict__ wbt,
                     float* __restrict__ out) {
    __shared__ unsigned short smem[24832];   // 49664 B
    unsigned short* sb    = smem;            // [32][60][8] = 15360 ushorts
    unsigned short* patch = smem + 15360;    // [32][296]   = 9472 ushorts

    const int tid = threadIdx.x;
    const int bx  = blockIdx.x;              // 0..391
    const int b   = bx / 98;
    const int r   = bx - b * 98;
    const int ty  = r / 7;
    const int tx  = r - ty * 7;
    const int h0  = ty * 4, w0 = tx * 8;

    const int lane = tid & 63;
    const int wv   = tid >> 6;        // 0..7
    const int nq   = wv & 3;          // oc quarter (16 oc)
    const int kh   = wv >> 2;         // K half (0: first, 1: second)
    const int ml   = lane & 15;       // A row (frag0) / B,C col (oc)
    const int kg   = lane >> 4;       // k-group 0..3 within k32 step
    const int py0  = ml >> 3, px0 = ml & 7;   // frag0 pixel (rows 0..15)

    // ---- phase 1: batch 4 independent x loads, eval bases, store + scatter ----
    float vv[4];
    #pragma unroll
    for (int j = 0; j < 4; ++j) {
        int i = tid + j * 512;        // 0..2047
        float val = 0.0f;
        if (i < 1920) {
            int c  = i / 60;
            int hp = i - c * 60;
            int hy = hp / 10;
            int hx = hp - hy * 10;
            int hh = h0 + hy - 1, ww = w0 + hx - 1;
            if ((unsigned)hh < 56u && (unsigned)ww < 56u)
                val = x[((b * 32 + c) * 56 + hh) * 56 + ww];
        }
        vv[j] = val;
    }
    #pragma unroll
    for (int j = 0; j < 4; ++j) {
        int i = tid + j * 512;
        if (i < 1920) {
            int c  = i / 60;
            int hp = i - c * 60;
            int hy = hp / 10;
            int hx = hp - hy * 10;
            float bs[8];
            eval_bases(vv[j], bs);
            bf16x8 pk;
            #pragma unroll
            for (int j2 = 0; j2 < 8; ++j2) pk[j2] = (short)f2bf(bs[j2]);
            *reinterpret_cast<bf16x8*>(&sb[i * 8]) = pk;
            // scatter x into patch: halo (hy,hx) -> m=(hy-kh)*8+(hx-kw), k=c*9+kh*3+kw
            unsigned short xb = f2bf(vv[j]);
            #pragma unroll
            for (int dkh = 0; dkh < 3; ++dkh) {
                int py = hy - dkh;
                if ((unsigned)py < 4u) {
                    #pragma unroll
                    for (int dkw = 0; dkw < 3; ++dkw) {
                        int px = hx - dkw;
                        if ((unsigned)px < 8u)
                            patch[(py * 8 + px) * 296 + c * 9 + dkh * 3 + dkw] = xb;
                    }
                }
            }
        }
    }
    __syncthreads();

    // spline A offsets (ushort units): step S = 9g+u reads p = 4S + kg
    //   -> c = 4g + (4u+kg)/9, tap = (4u+kg)%9.  aoff is g-independent.
    // frag1 (rows 16..31) = frag0 offset + 2 halo rows = +160 ushorts.
    int aoff[9];
    #pragma unroll
    for (int u = 0; u < 9; ++u) {
        int tt  = 4 * u + kg;         // 0..35
        int dc  = tt / 9;
        int tap = tt - dc * 9;
        int th  = tap / 3;
        int tw  = tap - th * 3;
        aoff[u] = (dc * 60 + (py0 + th) * 10 + (px0 + tw)) * 8;
    }

    f32x4 accS0 = {0.f, 0.f, 0.f, 0.f};
    f32x4 accS1 = {0.f, 0.f, 0.f, 0.f};
    f32x4 accB0 = {0.f, 0.f, 0.f, 0.f};
    f32x4 accB1 = {0.f, 0.f, 0.f, 0.f};

    // ---- spline GEMM: this wave's 36 k32-steps (S = kh*36 + g*9 + u) ----
    const unsigned short* bp = wst + ((nq * 72 + kh * 36) * 64 + lane) * 8;
    int cbase = kh * 4 * 1920;        // g starts at 4*kh: 4 channels * 480 ushorts each
    for (int g = 0; g < 4; ++g) {
        #pragma unroll
        for (int u = 0; u < 9; ++u) {
            bf16x8 a0 = *reinterpret_cast<const bf16x8*>(&sb[cbase + aoff[u]]);
            bf16x8 a1 = *reinterpret_cast<const bf16x8*>(&sb[cbase + aoff[u] + 160]);
            bf16x8 bw = *reinterpret_cast<const bf16x8*>(bp + (g * 9 + u) * 512);
            accS0 = MFMA16(a0, bw, accS0);
            accS1 = MFMA16(a1, bw, accS1);
        }
        cbase += 1920;
    }

    // ---- base GEMM: steps s in [5kh, 5kh+5-kh): kh=0 -> 0..4, kh=1 -> 5..8 ----
    {
        const unsigned short* ap0 = patch + ml * 296 + kg * 8;
        const unsigned short* ap1 = ap0 + 16 * 296;
        const unsigned short* bbp = wbt + (nq * 9 * 64 + lane) * 8;
        const int sbeg = kh ? 5 : 0;
        const int send = kh ? 9 : 5;
        for (int s = sbeg; s < send; ++s) {
            bf16x8 a0 = *reinterpret_cast<const bf16x8*>(ap0 + s * 32);
            bf16x8 a1 = *reinterpret_cast<const bf16x8*>(ap1 + s * 32);
            bf16x8 bw = *reinterpret_cast<const bf16x8*>(bbp + s * 512);
            accB0 = MFMA16(a0, bw, accB0);
            accB1 = MFMA16(a1, bw, accB1);
        }
    }

    // ---- cross-wave K reduction via LDS (SoA: [16 words][260], conflict-free) ----
    __syncthreads();                               // all sb/patch reads done
    float* red = reinterpret_cast<float*>(smem);   // 16*260*4 = 16640 B, inside dead sb
    const int idx = nq * 64 + lane;                // 0..255, same for the kh pair
    if (kh) {
        #pragma unroll
        for (int w = 0; w < 4; ++w) red[(0  + w) * 260 + idx] = accS0[w];
        #pragma unroll
        for (int w = 0; w < 4; ++w) red[(4  + w) * 260 + idx] = accS1[w];
        #pragma unroll
        for (int w = 0; w < 4; ++w) red[(8  + w) * 260 + idx] = accB0[w];
        #pragma unroll
        for (int w = 0; w < 4; ++w) red[(12 + w) * 260 + idx] = accB1[w];
    }
    __syncthreads();
    if (!kh) {
        #pragma unroll
        for (int w = 0; w < 4; ++w) accS0[w] += red[(0  + w) * 260 + idx];
        #pragma unroll
        for (int w = 0; w < 4; ++w) accS1[w] += red[(4  + w) * 260 + idx];
        #pragma unroll
        for (int w = 0; w < 4; ++w) accB0[w] += red[(8  + w) * 260 + idx];
        #pragma unroll
        for (int w = 0; w < 4; ++w) accB1[w] += red[(12 + w) * 260 + idx];

        // ---- epilogue: C/D row = kg*4 + reg (+16 for frag1), col = ml = oc ----
        const int oc  = nq * 16 + ml;
        const float scv = sc[oc];
        #pragma unroll
        for (int f = 0; f < 2; ++f) {
            const int rowb = f * 16 + kg * 4;      // regs 0..3 share py
            const int py   = rowb >> 3;
            const int pxb  = rowb & 7;             // 0 or 4
            float* ob = out + ((b * 64 + oc) * 56 + h0 + py) * 56 + w0 + pxb;
            f32x4 aB = f ? accB1 : accB0;
            f32x4 aS = f ? accS1 : accS0;
            f32x4 res;
            #pragma unroll
            for (int reg = 0; reg < 4; ++reg) {
                float bv = aB[reg];
                float si = bv / (1.0f + __expf(-bv));
                res[reg] = si + scv * aS[reg];
            }
            *reinterpret_cast<f32x4*>(ob) = res;
        }
    }
}

extern "C" void kernel_launch(void* const* d_in, const int* in_sizes, int n_in,
                              void* d_out, int out_size, void* d_ws, size_t ws_size,
                              hipStream_t stream) {
    const float* x  = (const float*)d_in[0];   // (4,32,56,56)
    const float* wb = (const float*)d_in[1];   // (64,32,3,3)
    const float* ws = (const float*)d_in[2];   // (64,288,8)
    const float* sc = (const float*)d_in[3];   // (64,)
    float* out = (float*)d_out;                // (4,64,56,56)

    unsigned short* wst = (unsigned short*)d_ws;   // 147456 bf16
    unsigned short* wbt = wst + 147456;            // 18432 bf16

    cvt_swz_kernel<<<648, 256, 0, stream>>>(ws, wb, wst, wbt);
    kan_mfma_kernel<<<392, 512, 0, stream>>>(x, sc, wst, wbt, out);
}